// Round 1
// baseline (483.871 us; speedup 1.0000x reference)
//
#include <hip/hip_runtime.h>
#include <math.h>

#define DI __device__ __forceinline__

typedef unsigned short u16;
typedef __attribute__((ext_vector_type(8))) u16 u16x8;
typedef __attribute__((ext_vector_type(4))) u16 u16x4;
typedef __attribute__((ext_vector_type(8))) __bf16 bf16x8;
typedef __attribute__((ext_vector_type(4))) float f32x4;

DI float bf2f(u16 u) {
  unsigned v = ((unsigned)u) << 16;
  float f; __builtin_memcpy(&f, &v, 4); return f;
}
DI u16 f2bf(float f) {
  unsigned u; __builtin_memcpy(&u, &f, 4);
  u += 0x7fff + ((u >> 16) & 1);   // RNE
  return (u16)(u >> 16);
}
DI f32x4 mfma16(bf16x8 a, bf16x8 b, f32x4 c) {
  return __builtin_amdgcn_mfma_f32_16x16x32_bf16(a, b, c, 0, 0, 0);
}

// ---------------- conversion: fp32 -> bf16 (elementwise) ----------------
__global__ __launch_bounds__(256) void cvt_bf16_k(const float* __restrict__ in,
                                                  u16* __restrict__ out, int n) {
  int i = (blockIdx.x * 256 + threadIdx.x) * 8;
  if (i >= n) return;
  float4 a = *(const float4*)(in + i);
  float4 b = *(const float4*)(in + i + 4);
  u16x8 o;
  o[0] = f2bf(a.x); o[1] = f2bf(a.y); o[2] = f2bf(a.z); o[3] = f2bf(a.w);
  o[4] = f2bf(b.x); o[5] = f2bf(b.y); o[6] = f2bf(b.z); o[7] = f2bf(b.w);
  *(u16x8*)(out + i) = o;
}

// ---------------- conversion: fp32 [K][N] -> bf16 [N][K] (transpose) ----------------
__global__ __launch_bounds__(256) void tcvt_k(const float* __restrict__ in,
                                              u16* __restrict__ out, int K, int N) {
  __shared__ float tile[32][33];
  int n0 = blockIdx.x * 32, k0 = blockIdx.y * 32;
  int tx = threadIdx.x & 31, ty = threadIdx.x >> 5;  // 32 x 8
  #pragma unroll
  for (int i = 0; i < 4; i++) {
    int kr = ty + i * 8;
    tile[kr][tx] = in[(size_t)(k0 + kr) * N + n0 + tx];
  }
  __syncthreads();
  #pragma unroll
  for (int i = 0; i < 4; i++) {
    int nr = ty + i * 8;
    out[(size_t)(n0 + nr) * K + k0 + tx] = f2bf(tile[tx][nr]);
  }
}

// ---------------- GEMM: C[M,N] = A[M,K](bf16) @ Bt[N,K](bf16)^T + bias, epilogue ----------------
// EPI 0: out = bf16(acc + bias)
// EPI 1: out = bf16(acc + bias + f32resid)
// EPI 2: out = bf16(gelu_exact(acc + bias))
// EPI 3: out = bf16(acc + bias + bf16resid)
template<int EPI>
__global__ __launch_bounds__(256) void gemm_bt_k(const u16* __restrict__ A,
                                                 const u16* __restrict__ Bt,
                                                 const float* __restrict__ bias,
                                                 const void* __restrict__ resid,
                                                 u16* __restrict__ out,
                                                 int M, int N, int K) {
  __shared__ __align__(16) u16 As[128 * 64];
  __shared__ __align__(16) u16 Bs[128 * 64];
  const int tid = threadIdx.x;
  const int lane = tid & 63, wid = tid >> 6;
  const int wm = (wid >> 1) * 64, wn = (wid & 1) * 64;
  const int bm = blockIdx.y * 128, bn = blockIdx.x * 128;
  const int r15 = lane & 15, kg = lane >> 4;

  f32x4 acc[4][4];
  #pragma unroll
  for (int i = 0; i < 4; i++)
    #pragma unroll
    for (int j = 0; j < 4; j++) acc[i][j] = (f32x4){0.f, 0.f, 0.f, 0.f};

  for (int kt = 0; kt < K; kt += 64) {
    #pragma unroll
    for (int c = 0; c < 4; c++) {
      int chunk = c * 256 + tid;
      int row = chunk >> 3, cg = chunk & 7;
      *(u16x8*)&As[row * 64 + cg * 8] =
          *(const u16x8*)&A[(size_t)(bm + row) * K + kt + cg * 8];
      *(u16x8*)&Bs[row * 64 + cg * 8] =
          *(const u16x8*)&Bt[(size_t)(bn + row) * K + kt + cg * 8];
    }
    __syncthreads();
    #pragma unroll
    for (int ks = 0; ks < 2; ks++) {
      bf16x8 af[4], bfr[4];
      #pragma unroll
      for (int i = 0; i < 4; i++)
        af[i] = *(const bf16x8*)&As[(wm + i * 16 + r15) * 64 + ks * 32 + kg * 8];
      #pragma unroll
      for (int i = 0; i < 4; i++)
        bfr[i] = *(const bf16x8*)&Bs[(wn + i * 16 + r15) * 64 + ks * 32 + kg * 8];
      #pragma unroll
      for (int i = 0; i < 4; i++)
        #pragma unroll
        for (int j = 0; j < 4; j++)
          acc[i][j] = mfma16(af[i], bfr[j], acc[i][j]);
    }
    __syncthreads();
  }

  #pragma unroll
  for (int i = 0; i < 4; i++) {
    int row0 = bm + wm + i * 16 + kg * 4;
    #pragma unroll
    for (int j = 0; j < 4; j++) {
      int col = bn + wn + j * 16 + r15;
      float bv = bias[col];
      #pragma unroll
      for (int q = 0; q < 4; q++) {
        int row = row0 + q;
        float v = acc[i][j][q] + bv;
        if (EPI == 1) v += ((const float*)resid)[(size_t)row * N + col];
        if (EPI == 2) v = 0.5f * v * (1.0f + erff(v * 0.70710678118f));
        if (EPI == 3) v += bf2f(((const u16*)resid)[(size_t)row * N + col]);
        out[(size_t)row * N + col] = f2bf(v);
      }
    }
  }
}

// ---------------- fused attention: per (32-row q-block, head, batch) ----------------
// Q,K,V: bf16 [B*S][H] (head h at col h*64). ctx: same layout, bf16.
__global__ __launch_bounds__(256) void attn_k(const u16* __restrict__ Q,
                                              const u16* __restrict__ Kk,
                                              const u16* __restrict__ V,
                                              const float* __restrict__ mask,
                                              u16* __restrict__ ctx) {
  __shared__ __align__(16) u16 sQ[32 * 72];
  __shared__ __align__(16) u16 sK[64 * 72];
  __shared__ __align__(16) u16 sVt[64 * 72];     // transposed: sVt[d][kpos]
  __shared__ __align__(16) u16 sS[32 * 520];     // scores then unnormalized probs
  __shared__ float sSum[32];
  const int t = threadIdx.x, lane = t & 63, wid = t >> 6;
  const int qb = blockIdx.x, h = blockIdx.y, b = blockIdx.z;
  const int r15 = lane & 15, kg = lane >> 4;
  const int mg = wid >> 1, half = wid & 1;
  const size_t headoff = (size_t)h * 64;

  {  // stage Q block (32 x 64)
    int row = t >> 3, d0 = (t & 7) * 8;
    *(u16x8*)&sQ[row * 72 + d0] =
        *(const u16x8*)&Q[((size_t)(b * 512 + qb * 32 + row)) * 1024 + headoff + d0];
  }

  // ---- phase A: S = Q K^T / 8 + mask ----
  for (int kt = 0; kt < 8; ++kt) {
    int row = t >> 2, d0 = (t & 3) * 16;
    const u16* src = &Kk[((size_t)(b * 512 + kt * 64 + row)) * 1024 + headoff + d0];
    *(u16x8*)&sK[row * 72 + d0] = *(const u16x8*)src;
    *(u16x8*)&sK[row * 72 + d0 + 8] = *(const u16x8*)(src + 8);
    __syncthreads();
    bf16x8 qf0 = *(const bf16x8*)&sQ[(mg * 16 + r15) * 72 + kg * 8];
    bf16x8 qf1 = *(const bf16x8*)&sQ[(mg * 16 + r15) * 72 + 32 + kg * 8];
    #pragma unroll
    for (int n2 = 0; n2 < 2; n2++) {
      int nt = half * 2 + n2;
      f32x4 sacc = (f32x4){0.f, 0.f, 0.f, 0.f};
      sacc = mfma16(qf0, *(const bf16x8*)&sK[(nt * 16 + r15) * 72 + kg * 8], sacc);
      sacc = mfma16(qf1, *(const bf16x8*)&sK[(nt * 16 + r15) * 72 + 32 + kg * 8], sacc);
      int col = kt * 64 + nt * 16 + r15;
      float mv = mask[b * 512 + col];
      #pragma unroll
      for (int q = 0; q < 4; q++) {
        int rl = mg * 16 + kg * 4 + q;
        sS[rl * 520 + col] = f2bf(sacc[q] * 0.125f + mv);
      }
    }
    __syncthreads();
  }

  // ---- phase B: row softmax (unnormalized; divide at the end) ----
  {
    int row = t >> 3, seg = t & 7;
    float mx = -1e30f;
    for (int j = 0; j < 64; j++)
      mx = fmaxf(mx, bf2f(sS[row * 520 + seg * 64 + j]));
    mx = fmaxf(mx, __shfl_xor(mx, 1));
    mx = fmaxf(mx, __shfl_xor(mx, 2));
    mx = fmaxf(mx, __shfl_xor(mx, 4));
    float sum = 0.f;
    for (int j = 0; j < 64; j++) {
      int idx = row * 520 + seg * 64 + j;
      float p = __expf(bf2f(sS[idx]) - mx);
      sum += p;
      sS[idx] = f2bf(p);
    }
    sum += __shfl_xor(sum, 1);
    sum += __shfl_xor(sum, 2);
    sum += __shfl_xor(sum, 4);
    if (seg == 0) sSum[row] = sum;
  }
  __syncthreads();

  // ---- phase C: ctx = P V ----
  f32x4 pacc[2];
  pacc[0] = (f32x4){0.f, 0.f, 0.f, 0.f};
  pacc[1] = (f32x4){0.f, 0.f, 0.f, 0.f};
  for (int vt = 0; vt < 8; ++vt) {
    int rowk = t >> 2, d0 = (t & 3) * 16;
    const u16* src = &V[((size_t)(b * 512 + vt * 64 + rowk)) * 1024 + headoff + d0];
    u16x8 v0 = *(const u16x8*)src;
    u16x8 v1 = *(const u16x8*)(src + 8);
    #pragma unroll
    for (int e = 0; e < 8; e++) {
      sVt[(d0 + e) * 72 + rowk] = v0[e];
      sVt[(d0 + 8 + e) * 72 + rowk] = v1[e];
    }
    __syncthreads();
    bf16x8 pf0 = *(const bf16x8*)&sS[(mg * 16 + r15) * 520 + vt * 64 + kg * 8];
    bf16x8 pf1 = *(const bf16x8*)&sS[(mg * 16 + r15) * 520 + vt * 64 + 32 + kg * 8];
    #pragma unroll
    for (int n2 = 0; n2 < 2; n2++) {
      int dcol = half * 32 + n2 * 16;
      pacc[n2] = mfma16(pf0, *(const bf16x8*)&sVt[(dcol + r15) * 72 + kg * 8], pacc[n2]);
      pacc[n2] = mfma16(pf1, *(const bf16x8*)&sVt[(dcol + r15) * 72 + 32 + kg * 8], pacc[n2]);
    }
    __syncthreads();
  }
  #pragma unroll
  for (int n2 = 0; n2 < 2; n2++) {
    int d = half * 32 + n2 * 16 + r15;
    #pragma unroll
    for (int q = 0; q < 4; q++) {
      int rl = mg * 16 + kg * 4 + q;
      float v = pacc[n2][q] / sSum[rl];
      ctx[((size_t)(b * 512 + qb * 32 + rl)) * 1024 + headoff + d] = f2bf(v);
    }
  }
}

// ---------------- LayerNorm over rows of 1024 ----------------
template<int OUTF32>
__global__ __launch_bounds__(256) void ln_k(const u16* __restrict__ in,
                                            const float* __restrict__ g,
                                            const float* __restrict__ be,
                                            void* __restrict__ out) {
  int row = blockIdx.x, t = threadIdx.x;
  const u16* rp = in + (size_t)row * 1024 + t * 4;
  u16x4 raw = *(const u16x4*)rp;
  float x[4];
  #pragma unroll
  for (int i = 0; i < 4; i++) x[i] = bf2f(raw[i]);
  float s = x[0] + x[1] + x[2] + x[3];
  float q = x[0]*x[0] + x[1]*x[1] + x[2]*x[2] + x[3]*x[3];
  #pragma unroll
  for (int off = 32; off; off >>= 1) {
    s += __shfl_down(s, off);
    q += __shfl_down(q, off);
  }
  __shared__ float rs_[4], rq_[4];
  int wid = t >> 6, lane = t & 63;
  if (!lane) { rs_[wid] = s; rq_[wid] = q; }
  __syncthreads();
  float S1 = rs_[0] + rs_[1] + rs_[2] + rs_[3];
  float S2 = rq_[0] + rq_[1] + rq_[2] + rq_[3];
  float mu = S1 * (1.0f / 1024.0f);
  float inv = rsqrtf(S2 * (1.0f / 1024.0f) - mu * mu + 1e-5f);
  #pragma unroll
  for (int i = 0; i < 4; i++) {
    int c = t * 4 + i;
    float y = (x[i] - mu) * inv * g[c] + be[c];
    if (OUTF32) ((float*)out)[(size_t)row * 1024 + c] = y;
    else        ((u16*)out)[(size_t)row * 1024 + c] = f2bf(y);
  }
}

// ---------------- launch ----------------
extern "C" void kernel_launch(void* const* d_in, const int* in_sizes, int n_in,
                              void* d_out, int out_size, void* d_ws, size_t ws_size,
                              hipStream_t stream) {
  const float* hidden = (const float*)d_in[0];
  const float* mask   = (const float*)d_in[1];
  const float* wq  = (const float*)d_in[2];  const float* bq  = (const float*)d_in[3];
  const float* wk  = (const float*)d_in[4];  const float* bk  = (const float*)d_in[5];
  const float* wv  = (const float*)d_in[6];  const float* bv  = (const float*)d_in[7];
  const float* wo  = (const float*)d_in[8];  const float* bo  = (const float*)d_in[9];
  const float* ln1g = (const float*)d_in[10]; const float* ln1b = (const float*)d_in[11];
  const float* wi  = (const float*)d_in[12]; const float* bi  = (const float*)d_in[13];
  const float* wo2 = (const float*)d_in[14]; const float* bo2 = (const float*)d_in[15];
  const float* ln2g = (const float*)d_in[16]; const float* ln2b = (const float*)d_in[17];

  char* ws = (char*)d_ws;
  size_t off = 0;
  auto alloc = [&](size_t elems) -> u16* {
    u16* p = (u16*)(ws + off);
    off += ((elems * 2 + 255) & ~(size_t)255);
    return p;
  };
  u16* Xb   = alloc(4194304);
  u16* WqT  = alloc(1048576);
  u16* WkT  = alloc(1048576);
  u16* WvT  = alloc(1048576);
  u16* WoT  = alloc(1048576);
  u16* WiT  = alloc(4194304);
  u16* Wo2T = alloc(4194304);
  u16* Qb   = alloc(4194304);
  u16* Kb   = alloc(4194304);
  u16* Vb   = alloc(4194304);
  u16* Ctx  = alloc(4194304);
  u16* AD   = alloc(4194304);
  u16* AO   = alloc(4194304);
  u16* Inter = alloc(16777216);
  u16* FD   = alloc(4194304);

  cvt_bf16_k<<<2048, 256, 0, stream>>>(hidden, Xb, 4194304);
  tcvt_k<<<dim3(32, 32),  256, 0, stream>>>(wq,  WqT,  1024, 1024);
  tcvt_k<<<dim3(32, 32),  256, 0, stream>>>(wk,  WkT,  1024, 1024);
  tcvt_k<<<dim3(32, 32),  256, 0, stream>>>(wv,  WvT,  1024, 1024);
  tcvt_k<<<dim3(32, 32),  256, 0, stream>>>(wo,  WoT,  1024, 1024);
  tcvt_k<<<dim3(128, 32), 256, 0, stream>>>(wi,  WiT,  1024, 4096);
  tcvt_k<<<dim3(32, 128), 256, 0, stream>>>(wo2, Wo2T, 4096, 1024);

  gemm_bt_k<0><<<dim3(8, 32), 256, 0, stream>>>(Xb, WqT, bq, nullptr, Qb, 4096, 1024, 1024);
  gemm_bt_k<0><<<dim3(8, 32), 256, 0, stream>>>(Xb, WkT, bk, nullptr, Kb, 4096, 1024, 1024);
  gemm_bt_k<0><<<dim3(8, 32), 256, 0, stream>>>(Xb, WvT, bv, nullptr, Vb, 4096, 1024, 1024);

  attn_k<<<dim3(16, 16, 8), 256, 0, stream>>>(Qb, Kb, Vb, mask, Ctx);

  gemm_bt_k<1><<<dim3(8, 32), 256, 0, stream>>>(Ctx, WoT, bo, hidden, AD, 4096, 1024, 1024);
  ln_k<0><<<4096, 256, 0, stream>>>(AD, ln1g, ln1b, AO);
  gemm_bt_k<2><<<dim3(32, 32), 256, 0, stream>>>(AO, WiT, bi, nullptr, Inter, 4096, 4096, 1024);
  gemm_bt_k<3><<<dim3(8, 32), 256, 0, stream>>>(Inter, Wo2T, bo2, AO, FD, 4096, 1024, 4096);
  ln_k<1><<<4096, 256, 0, stream>>>(FD, ln2g, ln2b, d_out);
}

// Round 2
// 454.903 us; speedup vs baseline: 1.0637x; 1.0637x over previous
//
#include <hip/hip_runtime.h>
#include <math.h>

#define DI __device__ __forceinline__

typedef unsigned short u16;
typedef __attribute__((ext_vector_type(8))) u16 u16x8;
typedef __attribute__((ext_vector_type(4))) u16 u16x4;
typedef __attribute__((ext_vector_type(8))) __bf16 bf16x8;
typedef __attribute__((ext_vector_type(4))) float f32x4;

typedef const __attribute__((address_space(1))) unsigned int g_u32;
typedef __attribute__((address_space(3))) unsigned int l_u32;

DI float bf2f(u16 u) {
  unsigned v = ((unsigned)u) << 16;
  float f; __builtin_memcpy(&f, &v, 4); return f;
}
DI u16 f2bf(float f) {
  unsigned u; __builtin_memcpy(&u, &f, 4);
  u += 0x7fff + ((u >> 16) & 1);   // RNE
  return (u16)(u >> 16);
}
DI f32x4 mfma16(bf16x8 a, bf16x8 b, f32x4 c) {
  return __builtin_amdgcn_mfma_f32_16x16x32_bf16(a, b, c, 0, 0, 0);
}
DI void gl16(const void* g, const u16* lds) {   // async global->LDS, 16B/lane
  __builtin_amdgcn_global_load_lds((g_u32*)g, (l_u32*)lds, 16, 0, 0);
}

// ---------------- conversion: fp32 -> bf16 (elementwise) ----------------
__global__ __launch_bounds__(256) void cvt_bf16_k(const float* __restrict__ in,
                                                  u16* __restrict__ out, int n) {
  int i = (blockIdx.x * 256 + threadIdx.x) * 8;
  if (i >= n) return;
  float4 a = *(const float4*)(in + i);
  float4 b = *(const float4*)(in + i + 4);
  u16x8 o;
  o[0] = f2bf(a.x); o[1] = f2bf(a.y); o[2] = f2bf(a.z); o[3] = f2bf(a.w);
  o[4] = f2bf(b.x); o[5] = f2bf(b.y); o[6] = f2bf(b.z); o[7] = f2bf(b.w);
  *(u16x8*)(out + i) = o;
}

// ---------------- conversion: fp32 [K][N] -> bf16 [N][K] (transpose) ----------------
__global__ __launch_bounds__(256) void tcvt_k(const float* __restrict__ in,
                                              u16* __restrict__ out, int K, int N) {
  __shared__ float tile[32][33];
  int n0 = blockIdx.x * 32, k0 = blockIdx.y * 32;
  int tx = threadIdx.x & 31, ty = threadIdx.x >> 5;  // 32 x 8
  #pragma unroll
  for (int i = 0; i < 4; i++) {
    int kr = ty + i * 8;
    tile[kr][tx] = in[(size_t)(k0 + kr) * N + n0 + tx];
  }
  __syncthreads();
  #pragma unroll
  for (int i = 0; i < 4; i++) {
    int nr = ty + i * 8;
    out[(size_t)(n0 + nr) * K + k0 + tx] = f2bf(tile[tx][nr]);
  }
}

__global__ __launch_bounds__(256) void pack_bias_k(const float* __restrict__ b0,
                                                   const float* __restrict__ b1,
                                                   const float* __restrict__ b2,
                                                   float* __restrict__ out) {
  int i = blockIdx.x * 256 + threadIdx.x;   // grid 12 -> 3072
  float v = (i < 1024) ? b0[i] : (i < 2048 ? b1[i - 1024] : b2[i - 2048]);
  out[i] = v;
}

// ---------------- GEMM: C[M,N] = A[M,K](bf16) @ Bt[N,K](bf16)^T + bias, epilogue ----------------
// m97 structure: 128x128 tile, BK=64, 4 waves, global_load_lds width-16 staging.
// EPI 0: out = bf16(acc + bias)
// EPI 1: out = bf16(acc + bias + f32resid)
// EPI 2: out = bf16(gelu_exact(acc + bias))
// EPI 3: out = bf16(acc + bias + bf16resid)
template<int EPI>
__global__ __launch_bounds__(256) void gemm_bt_k(const u16* __restrict__ A,
                                                 const u16* __restrict__ Bt,
                                                 const float* __restrict__ bias,
                                                 const void* __restrict__ resid,
                                                 u16* __restrict__ out,
                                                 int M, int N, int K) {
  __shared__ __align__(16) u16 As[128 * 64];
  __shared__ __align__(16) u16 Bs[128 * 64];
  const int tid = threadIdx.x;
  const int lane = tid & 63, wid = tid >> 6;
  const int wm = (wid >> 1) * 64, wn = (wid & 1) * 64;
  const int bm = blockIdx.y * 128, bn = blockIdx.x * 128;
  const int r15 = lane & 15, kg = lane >> 4;

  // staging geometry: 16 chunks of 1024B per matrix; wave wid takes chunks c*4+wid.
  // chunk ci covers rows [ci*8, ci*8+8), lane l -> row ci*8 + (l>>3), colbyte (l&7)*16.
  const int srow = lane >> 3;
  const int scolb = (lane & 7) << 4;

  f32x4 acc[4][4];
  #pragma unroll
  for (int i = 0; i < 4; i++)
    #pragma unroll
    for (int j = 0; j < 4; j++) acc[i][j] = (f32x4){0.f, 0.f, 0.f, 0.f};

  for (int kt = 0; kt < K; kt += 64) {
    #pragma unroll
    for (int c = 0; c < 4; c++) {
      int chunk = (c << 2) | wid;
      int row = (chunk << 3) + srow;
      gl16((const char*)A + ((size_t)(bm + row) * K + kt) * 2 + scolb,
           (const u16*)((const char*)As + (chunk << 10)));
      gl16((const char*)Bt + ((size_t)(bn + row) * K + kt) * 2 + scolb,
           (const u16*)((const char*)Bs + (chunk << 10)));
    }
    __syncthreads();   // drains vmcnt (global_load_lds) + barrier
    #pragma unroll
    for (int ks = 0; ks < 2; ks++) {
      bf16x8 af[4], bfr[4];
      #pragma unroll
      for (int i = 0; i < 4; i++)
        af[i] = *(const bf16x8*)&As[(wm + i * 16 + r15) * 64 + ks * 32 + kg * 8];
      #pragma unroll
      for (int i = 0; i < 4; i++)
        bfr[i] = *(const bf16x8*)&Bs[(wn + i * 16 + r15) * 64 + ks * 32 + kg * 8];
      #pragma unroll
      for (int i = 0; i < 4; i++)
        #pragma unroll
        for (int j = 0; j < 4; j++)
          acc[i][j] = mfma16(af[i], bfr[j], acc[i][j]);
    }
    __syncthreads();
  }

  #pragma unroll
  for (int i = 0; i < 4; i++) {
    int row0 = bm + wm + i * 16 + kg * 4;
    #pragma unroll
    for (int j = 0; j < 4; j++) {
      int col = bn + wn + j * 16 + r15;
      float bv = bias[col];
      #pragma unroll
      for (int q = 0; q < 4; q++) {
        int row = row0 + q;
        float v = acc[i][j][q] + bv;
        if (EPI == 1) v += ((const float*)resid)[(size_t)row * N + col];
        if (EPI == 2) v = 0.5f * v * (1.0f + erff(v * 0.70710678118f));
        if (EPI == 3) v += bf2f(((const u16*)resid)[(size_t)row * N + col]);
        out[(size_t)row * N + col] = f2bf(v);
      }
    }
  }
}

// ---------------- fused attention: per (32-row q-block, head, batch) ----------------
// QKV: bf16 [B*S][3072]; Q at col h*64, K at 1024+h*64, V at 2048+h*64. ctx: [B*S][1024] bf16.
__global__ __launch_bounds__(256) void attn_k(const u16* __restrict__ QKV,
                                              const float* __restrict__ mask,
                                              u16* __restrict__ ctx) {
  __shared__ __align__(16) u16 sQ[32 * 72];
  __shared__ __align__(16) u16 sK[64 * 72];
  __shared__ __align__(16) u16 sVt[64 * 72];     // transposed: sVt[d][kpos]
  __shared__ __align__(16) u16 sS[32 * 520];     // scores then unnormalized probs
  __shared__ float sSum[32];
  const int t = threadIdx.x, lane = t & 63, wid = t >> 6;
  const int qb = blockIdx.x, h = blockIdx.y, b = blockIdx.z;
  const int r15 = lane & 15, kg = lane >> 4;
  const int mg = wid >> 1, half = wid & 1;
  const size_t qoff = (size_t)h * 64;
  const size_t koff = 1024 + qoff, voff = 2048 + qoff;

  {  // stage Q block (32 x 64)
    int row = t >> 3, d0 = (t & 7) * 8;
    *(u16x8*)&sQ[row * 72 + d0] =
        *(const u16x8*)&QKV[((size_t)(b * 512 + qb * 32 + row)) * 3072 + qoff + d0];
  }

  // ---- phase A: S = Q K^T / 8 + mask ----
  for (int kt = 0; kt < 8; ++kt) {
    int row = t >> 2, d0 = (t & 3) * 16;
    const u16* src = &QKV[((size_t)(b * 512 + kt * 64 + row)) * 3072 + koff + d0];
    *(u16x8*)&sK[row * 72 + d0] = *(const u16x8*)src;
    *(u16x8*)&sK[row * 72 + d0 + 8] = *(const u16x8*)(src + 8);
    __syncthreads();
    bf16x8 qf0 = *(const bf16x8*)&sQ[(mg * 16 + r15) * 72 + kg * 8];
    bf16x8 qf1 = *(const bf16x8*)&sQ[(mg * 16 + r15) * 72 + 32 + kg * 8];
    #pragma unroll
    for (int n2 = 0; n2 < 2; n2++) {
      int nt = half * 2 + n2;
      f32x4 sacc = (f32x4){0.f, 0.f, 0.f, 0.f};
      sacc = mfma16(qf0, *(const bf16x8*)&sK[(nt * 16 + r15) * 72 + kg * 8], sacc);
      sacc = mfma16(qf1, *(const bf16x8*)&sK[(nt * 16 + r15) * 72 + 32 + kg * 8], sacc);
      int col = kt * 64 + nt * 16 + r15;
      float mv = mask[b * 512 + col];
      #pragma unroll
      for (int q = 0; q < 4; q++) {
        int rl = mg * 16 + kg * 4 + q;
        sS[rl * 520 + col] = f2bf(sacc[q] * 0.125f + mv);
      }
    }
    __syncthreads();
  }

  // ---- phase B: row softmax (unnormalized; divide at the end) ----
  {
    int row = t >> 3, seg = t & 7;
    float mx = -1e30f;
    for (int j = 0; j < 64; j++)
      mx = fmaxf(mx, bf2f(sS[row * 520 + seg * 64 + j]));
    mx = fmaxf(mx, __shfl_xor(mx, 1));
    mx = fmaxf(mx, __shfl_xor(mx, 2));
    mx = fmaxf(mx, __shfl_xor(mx, 4));
    float sum = 0.f;
    for (int j = 0; j < 64; j++) {
      int idx = row * 520 + seg * 64 + j;
      float p = __expf(bf2f(sS[idx]) - mx);
      sum += p;
      sS[idx] = f2bf(p);
    }
    sum += __shfl_xor(sum, 1);
    sum += __shfl_xor(sum, 2);
    sum += __shfl_xor(sum, 4);
    if (seg == 0) sSum[row] = sum;
  }
  __syncthreads();

  // ---- phase C: ctx = P V ----
  f32x4 pacc[2];
  pacc[0] = (f32x4){0.f, 0.f, 0.f, 0.f};
  pacc[1] = (f32x4){0.f, 0.f, 0.f, 0.f};
  for (int vt = 0; vt < 8; ++vt) {
    int rowk = t >> 2, d0 = (t & 3) * 16;
    const u16* src = &QKV[((size_t)(b * 512 + vt * 64 + rowk)) * 3072 + voff + d0];
    u16x8 v0 = *(const u16x8*)src;
    u16x8 v1 = *(const u16x8*)(src + 8);
    #pragma unroll
    for (int e = 0; e < 8; e++) {
      sVt[(d0 + e) * 72 + rowk] = v0[e];
      sVt[(d0 + 8 + e) * 72 + rowk] = v1[e];
    }
    __syncthreads();
    bf16x8 pf0 = *(const bf16x8*)&sS[(mg * 16 + r15) * 520 + vt * 64 + kg * 8];
    bf16x8 pf1 = *(const bf16x8*)&sS[(mg * 16 + r15) * 520 + vt * 64 + 32 + kg * 8];
    #pragma unroll
    for (int n2 = 0; n2 < 2; n2++) {
      int dcol = half * 32 + n2 * 16;
      pacc[n2] = mfma16(pf0, *(const bf16x8*)&sVt[(dcol + r15) * 72 + kg * 8], pacc[n2]);
      pacc[n2] = mfma16(pf1, *(const bf16x8*)&sVt[(dcol + r15) * 72 + 32 + kg * 8], pacc[n2]);
    }
    __syncthreads();
  }
  #pragma unroll
  for (int n2 = 0; n2 < 2; n2++) {
    int d = half * 32 + n2 * 16 + r15;
    #pragma unroll
    for (int q = 0; q < 4; q++) {
      int rl = mg * 16 + kg * 4 + q;
      float v = pacc[n2][q] / sSum[rl];
      ctx[((size_t)(b * 512 + qb * 32 + rl)) * 1024 + qoff + d] = f2bf(v);
    }
  }
}

// ---------------- LayerNorm over rows of 1024 ----------------
template<int OUTF32>
__global__ __launch_bounds__(256) void ln_k(const u16* __restrict__ in,
                                            const float* __restrict__ g,
                                            const float* __restrict__ be,
                                            void* __restrict__ out) {
  int row = blockIdx.x, t = threadIdx.x;
  const u16* rp = in + (size_t)row * 1024 + t * 4;
  u16x4 raw = *(const u16x4*)rp;
  float x[4];
  #pragma unroll
  for (int i = 0; i < 4; i++) x[i] = bf2f(raw[i]);
  float s = x[0] + x[1] + x[2] + x[3];
  float q = x[0]*x[0] + x[1]*x[1] + x[2]*x[2] + x[3]*x[3];
  #pragma unroll
  for (int off = 32; off; off >>= 1) {
    s += __shfl_down(s, off);
    q += __shfl_down(q, off);
  }
  __shared__ float rs_[4], rq_[4];
  int wid = t >> 6, lane = t & 63;
  if (!lane) { rs_[wid] = s; rq_[wid] = q; }
  __syncthreads();
  float S1 = rs_[0] + rs_[1] + rs_[2] + rs_[3];
  float S2 = rq_[0] + rq_[1] + rq_[2] + rq_[3];
  float mu = S1 * (1.0f / 1024.0f);
  float inv = rsqrtf(S2 * (1.0f / 1024.0f) - mu * mu + 1e-5f);
  #pragma unroll
  for (int i = 0; i < 4; i++) {
    int c = t * 4 + i;
    float y = (x[i] - mu) * inv * g[c] + be[c];
    if (OUTF32) ((float*)out)[(size_t)row * 1024 + c] = y;
    else        ((u16*)out)[(size_t)row * 1024 + c] = f2bf(y);
  }
}

// ---------------- launch ----------------
extern "C" void kernel_launch(void* const* d_in, const int* in_sizes, int n_in,
                              void* d_out, int out_size, void* d_ws, size_t ws_size,
                              hipStream_t stream) {
  const float* hidden = (const float*)d_in[0];
  const float* mask   = (const float*)d_in[1];
  const float* wq  = (const float*)d_in[2];  const float* bq  = (const float*)d_in[3];
  const float* wk  = (const float*)d_in[4];  const float* bk  = (const float*)d_in[5];
  const float* wv  = (const float*)d_in[6];  const float* bv  = (const float*)d_in[7];
  const float* wo  = (const float*)d_in[8];  const float* bo  = (const float*)d_in[9];
  const float* ln1g = (const float*)d_in[10]; const float* ln1b = (const float*)d_in[11];
  const float* wi  = (const float*)d_in[12]; const float* bi  = (const float*)d_in[13];
  const float* wo2 = (const float*)d_in[14]; const float* bo2 = (const float*)d_in[15];
  const float* ln2g = (const float*)d_in[16]; const float* ln2b = (const float*)d_in[17];

  char* ws = (char*)d_ws;
  size_t off = 0;
  auto alloc = [&](size_t elems) -> u16* {
    u16* p = (u16*)(ws + off);
    off += ((elems * 2 + 255) & ~(size_t)255);
    return p;
  };
  u16* Xb    = alloc(4194304);    // [4096][1024] bf16
  u16* WqkvT = alloc(3145728);    // [3072][1024] bf16 (wq^T | wk^T | wv^T)
  u16* WoT   = alloc(1048576);
  u16* WiT   = alloc(4194304);
  u16* Wo2T  = alloc(4194304);
  u16* QKVb  = alloc(12582912);   // [4096][3072] bf16
  u16* Ctx   = alloc(4194304);
  u16* AD    = alloc(4194304);
  u16* AO    = alloc(4194304);
  u16* Inter = alloc(16777216);
  u16* FD    = alloc(4194304);
  float* bqkv = (float*)(ws + off); off += 3072 * 4;

  cvt_bf16_k<<<2048, 256, 0, stream>>>(hidden, Xb, 4194304);
  tcvt_k<<<dim3(32, 32),  256, 0, stream>>>(wq,  WqkvT,                1024, 1024);
  tcvt_k<<<dim3(32, 32),  256, 0, stream>>>(wk,  WqkvT + 1024 * 1024,  1024, 1024);
  tcvt_k<<<dim3(32, 32),  256, 0, stream>>>(wv,  WqkvT + 2048 * 1024,  1024, 1024);
  tcvt_k<<<dim3(32, 32),  256, 0, stream>>>(wo,  WoT,  1024, 1024);
  tcvt_k<<<dim3(128, 32), 256, 0, stream>>>(wi,  WiT,  1024, 4096);
  tcvt_k<<<dim3(32, 128), 256, 0, stream>>>(wo2, Wo2T, 4096, 1024);
  pack_bias_k<<<12, 256, 0, stream>>>(bq, bk, bv, bqkv);

  // fused QKV projection: [4096,1024] @ [1024,3072] -> [4096,3072]
  gemm_bt_k<0><<<dim3(24, 32), 256, 0, stream>>>(Xb, WqkvT, bqkv, nullptr, QKVb, 4096, 3072, 1024);

  attn_k<<<dim3(16, 16, 8), 256, 0, stream>>>(QKVb, mask, Ctx);

  gemm_bt_k<1><<<dim3(8, 32), 256, 0, stream>>>(Ctx, WoT, bo, hidden, AD, 4096, 1024, 1024);
  ln_k<0><<<4096, 256, 0, stream>>>(AD, ln1g, ln1b, AO);
  gemm_bt_k<2><<<dim3(32, 32), 256, 0, stream>>>(AO, WiT, bi, nullptr, Inter, 4096, 4096, 1024);
  gemm_bt_k<3><<<dim3(8, 32), 256, 0, stream>>>(Inter, Wo2T, bo2, AO, FD, 4096, 1024, 4096);
  ln_k<1><<<4096, 256, 0, stream>>>(FD, ln2g, ln2b, d_out);
}